// Round 8
// baseline (170.905 us; speedup 1.0000x reference)
//
#include <hip/hip_runtime.h>
#include <stdint.h>
#include <stddef.h>

#define T_ 2048
#define D_ 1024
#define H_ 16

typedef __attribute__((ext_vector_type(8))) short short8;
typedef __attribute__((ext_vector_type(4))) float f32x4;
typedef __attribute__((ext_vector_type(4))) short s16x4;

__device__ __forceinline__ unsigned short f2bf(float f){
  union { float f; unsigned u; } c; c.f = f;
  unsigned u = c.u;
  return (unsigned short)((u + 0x7fffu + ((u >> 16) & 1u)) >> 16);
}

__device__ __forceinline__ unsigned pk_bf16(float lo, float hi){
  unsigned r;
  asm("v_cvt_pk_bf16_f32 %0, %1, %2" : "=v"(r) : "v"(lo), "v"(hi));
  return r;
}

__device__ __forceinline__ float fexp2(float x){
#if __has_builtin(__builtin_amdgcn_exp2f)
  return __builtin_amdgcn_exp2f(x);
#else
  return exp2f(x);
#endif
}

__device__ __forceinline__ f32x4 mfma16(short8 a, short8 b, f32x4 c){
  return __builtin_amdgcn_mfma_f32_16x16x32_bf16(a, b, c, 0, 0, 0);
}

// async global->LDS, 16B per lane; LDS dest must be uniform-base + lane*16
__device__ __forceinline__ void gload16(const void* g, void* l){
  __builtin_amdgcn_global_load_lds(
      (const __attribute__((address_space(1))) unsigned*)g,
      (__attribute__((address_space(3))) unsigned*)l, 16, 0, 0);
}

// ---------------- prep: f32 -> bf16 conversions + rope table ----------------
__global__ __launch_bounds__(256) void k_prep(const float* __restrict__ x,
    const float* __restrict__ wq, const float* __restrict__ wk,
    const float* __restrict__ wv, const float* __restrict__ wo,
    unsigned short* __restrict__ xb, unsigned short* __restrict__ wqkv,
    unsigned short* __restrict__ wob, float* __restrict__ tab)
{
  if (blockIdx.x < 256){                      // rope table [T][32] sin|cos
    int i = blockIdx.x * 256 + threadIdx.x;
    int t = i >> 5, p = i & 31;
    float ang = (float)t * powf(10000.0f, -(float)p * (1.0f / 32.0f));
    tab[i] = sinf(ang);
    tab[T_ * 32 + i] = cosf(ang);
  }
  const long long NX = 4194304LL, NW = 1048576LL;
  long long base = ((long long)blockIdx.x * 256 + threadIdx.x) * 4;
  const float* s; unsigned short* d;
  if (base < NX){ s = x + base; d = xb + base; }
  else if (base < NX + 3*NW){
    long long j = base - NX;
    if (j < NW) s = wq + j;
    else if (j < 2*NW) s = wk + (j - NW);
    else s = wv + (j - 2*NW);
    d = wqkv + j;
  } else if (base < NX + 4*NW){
    long long j = base - NX - 3*NW;
    s = wo + j; d = wob + j;
  } else return;
  float4 v = *(const float4*)s;
  d[0] = f2bf(v.x); d[1] = f2bf(v.y); d[2] = f2bf(v.z); d[3] = f2bf(v.w);
}

// ---------------- shared GEMM core: C[128x128] = A[128xK] * Bm[128xK]^T -------
// LDS: linear dest via global_load_lds, source pre-swizzled (slot ^= row&7),
// reads swizzled -> conflict-free ds_read_b128 (rule #21 both-sides swizzle).
__device__ __forceinline__ void gemm_core(const unsigned short* __restrict__ A,
    const unsigned short* __restrict__ Bm, int m0, int n0,
    unsigned short* lA, unsigned short* lB, f32x4 (&acc)[4][4])
{
  const int tid = threadIdx.x, lane = tid & 63, wave = tid >> 6;
  const int wr = wave >> 1, wc = wave & 1;
  for (int mi = 0; mi < 4; ++mi)
    for (int ni = 0; ni < 4; ++ni)
      acc[mi][ni] = (f32x4){0.f, 0.f, 0.f, 0.f};
  for (int k0 = 0; k0 < 1024; k0 += 64){
    __syncthreads();
#pragma unroll
    for (int p = 0; p < 4; ++p){
      int c = p * 256 + tid, r = c >> 3, s = c & 7;
      int gs = (s ^ (r & 7)) << 3;
      gload16(A + (size_t)(m0 + r) * 1024 + k0 + gs, lA + c * 8);
      gload16(Bm + (size_t)(n0 + r) * 1024 + k0 + gs, lB + c * 8);
    }
    __syncthreads();
#pragma unroll
    for (int kk = 0; kk < 2; ++kk){
      int kslot = kk * 4 + (lane >> 4);
      short8 af[4], bf[4];
#pragma unroll
      for (int mi = 0; mi < 4; ++mi){
        int row = wr * 64 + mi * 16 + (lane & 15);
        af[mi] = *(const short8*)(lA + row * 64 + ((kslot ^ (row & 7)) << 3));
      }
#pragma unroll
      for (int ni = 0; ni < 4; ++ni){
        int row = wc * 64 + ni * 16 + (lane & 15);
        bf[ni] = *(const short8*)(lB + row * 64 + ((kslot ^ (row & 7)) << 3));
      }
#pragma unroll
      for (int mi = 0; mi < 4; ++mi)
#pragma unroll
        for (int ni = 0; ni < 4; ++ni)
          acc[mi][ni] = mfma16(af[mi], bf[ni], acc[mi][ni]);
    }
  }
}

// ---------------- fused QKV projection + bias + RoPE ----------------
// Q is pre-scaled by 0.125*log2(e) (softmax in exp2 domain).
// V is stored TRANSPOSED: [b,h,d,t], vector 8B stores.
__global__ __launch_bounds__(256) void k_qkv(const unsigned short* __restrict__ xb,
    const unsigned short* __restrict__ wqkv,
    const float* __restrict__ bq, const float* __restrict__ bk, const float* __restrict__ bv,
    const float* __restrict__ tab,
    unsigned short* __restrict__ Qw, unsigned short* __restrict__ Kw,
    unsigned short* __restrict__ Vw)
{
  __shared__ alignas(16) unsigned short lA[128 * 64];
  __shared__ alignas(16) unsigned short lB[128 * 64];
  int m0 = blockIdx.y * 128, n0 = blockIdx.x * 128;
  f32x4 acc[4][4];
  gemm_core(xb, wqkv, m0, n0, lA, lB, acc);
  int lane = threadIdx.x & 63, wave = threadIdx.x >> 6;
  int wr = wave >> 1, wc = wave & 1;
  int mat = n0 >> 10;                       // 0=Q 1=K 2=V
  const float* bias = (mat == 0) ? bq : (mat == 1 ? bk : bv);
  const float* st = tab; const float* ct = tab + T_ * 32;
  if (mat < 2){
    unsigned short* Out = (mat == 0) ? Qw : Kw;
    float qs = (mat == 0) ? 0.18033688011116f : 1.0f;   // (1/8)*log2e
    for (int mi = 0; mi < 4; ++mi){
      for (int ni = 0; ni < 4; ++ni){
        int col = n0 + wc * 64 + ni * 16 + (lane & 15);
        int nn = col & 1023, h = nn >> 6, dd = nn & 63;
        float bsv = bias[nn];
        f32x4 v4 = acc[mi][ni];
#pragma unroll
        for (int r = 0; r < 4; ++r){
          int m = m0 + wr * 64 + mi * 16 + ((lane >> 4) << 2) + r;
          int bb = m >> 11, t = m & 2047;
          float v = v4[r] + bsv;
          float u = __shfl_xor(v, 1);       // rope partner col is lane^1
          int p = dd >> 1;
          float sv = st[t * 32 + p], cv = ct[t * 32 + p];
          float res = (dd & 1) ? (u * sv + v * cv) : (v * cv - u * sv);
          Out[((size_t)(bb * H_ + h) * T_ + t) * 64 + dd] = f2bf(res * qs);
        }
      }
    }
  } else {
    for (int mi = 0; mi < 4; ++mi){
      for (int ni = 0; ni < 4; ++ni){
        int col = n0 + wc * 64 + ni * 16 + (lane & 15);
        int nn = col & 1023, h = nn >> 6, dd = nn & 63;
        float bsv = bias[nn];
        int mb = m0 + wr * 64 + mi * 16 + ((lane >> 4) << 2);
        int bb = mb >> 11, t = mb & 2047;
        f32x4 v4 = acc[mi][ni];
        s16x4 o;
#pragma unroll
        for (int r = 0; r < 4; ++r) o[r] = (short)f2bf(v4[r] + bsv);
        *(s16x4*)(Vw + ((size_t)((bb * H_ + h) * 64 + dd)) * T_ + t) = o;
      }
    }
  }
}

// ---------------- flash attention (causal), swapped-QK^T, in-register P -------
// 1-WAVE workgroups, ZERO LDS, ZERO barriers. Each wave reads every K/V tile
// element exactly once -> LDS staging buys no intra-wave reuse, only barrier
// cost. K/V fragments load global->VGPR directly (L2-resident across waves);
// with no barriers and no LDS-writer aliasing the compiler pipelines loads
// across tiles, and 8 independent waves/CU provide the latency-hiding TLP
// that barriered blocks could not.
__global__ __launch_bounds__(64, 2) void k_attn(const unsigned short* __restrict__ Qw,
    const unsigned short* __restrict__ Kw, const unsigned short* __restrict__ Vt_g,
    unsigned short* __restrict__ ctxb)
{
  // XCD swizzle: 256 consecutive blocks per XCD = 4 bh x 64 q-blocks (K/V
  // working set 2MB per XCD L2); heavy q-blocks first for causal balance.
  int bid = blockIdx.x;
  int swz = (bid & 7) * 256 + (bid >> 3);
  int bh = swz >> 6;
  int qtb = 63 - (swz & 63);
  int lane = threadIdx.x;                   // 64-thread block = one wave
  const unsigned short* Qb = Qw + (size_t)bh * T_ * 64;
  const unsigned short* Kb = Kw + (size_t)bh * T_ * 64;
  const unsigned short* Vb = Vt_g + (size_t)bh * 64 * T_;
  int q0 = qtb * 32;                        // this wave's 32 q-rows

  short8 qf[2][2];
#pragma unroll
  for (int mi = 0; mi < 2; ++mi){
    const unsigned short* qp = Qb + (size_t)(q0 + mi * 16 + (lane & 15)) * 64 + ((lane >> 4) << 3);
    qf[mi][0] = *(const short8*)qp;
    qf[mi][1] = *(const short8*)(qp + 32);
  }
  float mr[2] = {-1e30f, -1e30f}, lr[2] = {0.f, 0.f};
  f32x4 acc_o[2][4];
#pragma unroll
  for (int mi = 0; mi < 2; ++mi)
#pragma unroll
    for (int df = 0; df < 4; ++df) acc_o[mi][df] = (f32x4){0.f, 0.f, 0.f, 0.f};

  const int src0 = ((lane >> 4) & 1) * 32 + (lane & 15);
  const int src1 = src0 + 16;
  const bool hiHalf = lane >= 32;
  int ntiles = (qtb >> 1) + 1;              // exact causal tile count

  for (int jt = 0; jt < ntiles; ++jt){
    int j0 = jt * 64;
    bool need_mask = (j0 + 63 > q0);

    // K fragments: row j = j0+jf*16+(lane&15), d-chunk = (kk*4+(lane>>4))*8
    short8 kf[2][4];
#pragma unroll
    for (int kk = 0; kk < 2; ++kk)
#pragma unroll
      for (int jf = 0; jf < 4; ++jf)
        kf[kk][jf] = *(const short8*)(Kb
            + (size_t)(j0 + jf * 16 + (lane & 15)) * 64
            + ((kk * 4 + (lane >> 4)) << 3));
    // V^T fragments (issued early; consumed in PV after softmax)
    short8 vf[2][4];
#pragma unroll
    for (int kk = 0; kk < 2; ++kk)
#pragma unroll
      for (int df = 0; df < 4; ++df)
        vf[kk][df] = *(const short8*)(Vb
            + (size_t)(df * 16 + (lane & 15)) * T_
            + j0 + ((kk * 4 + (lane >> 4)) << 3));

    // S^T = K @ Q^T : frag rows = j, cols = q (col = lane&15)
    f32x4 accs[2][4];
#pragma unroll
    for (int mi = 0; mi < 2; ++mi)
#pragma unroll
      for (int jf = 0; jf < 4; ++jf) accs[mi][jf] = (f32x4){0.f, 0.f, 0.f, 0.f};
#pragma unroll
    for (int kk = 0; kk < 2; ++kk)
#pragma unroll
      for (int mi = 0; mi < 2; ++mi)
#pragma unroll
        for (int jf = 0; jf < 4; ++jf)
          accs[mi][jf] = mfma16(kf[kk][jf], qf[mi][kk], accs[mi][jf]);

    // online softmax per q (lane-local for col q = lane&15), defer-max THR=8
    unsigned w0[2][4], w1[2][4];
#pragma unroll
    for (int mi = 0; mi < 2; ++mi){
      int qa = q0 + mi * 16 + (lane & 15);
      float s[4][4];
      float mx = -1e30f;
#pragma unroll
      for (int jf = 0; jf < 4; ++jf)
#pragma unroll
        for (int r = 0; r < 4; ++r){
          float sv = accs[mi][jf][r];
          if (need_mask){
            int ja = j0 + jf * 16 + ((lane >> 4) << 2) + r;
            if (ja > qa) sv = -1e30f;
          }
          s[jf][r] = sv;
          mx = fmaxf(mx, sv);
        }
      mx = fmaxf(mx, __shfl_xor(mx, 16));
      mx = fmaxf(mx, __shfl_xor(mx, 32));
      float mn = mr[mi];
      if (!__all(mx <= mn + 8.0f)){        // rescale only on real max growth
        mn = fmaxf(mn, mx);
        float sc = fexp2(mr[mi] - mn);
        mr[mi] = mn;
        lr[mi] *= sc;
#pragma unroll
        for (int df = 0; df < 4; ++df){
          f32x4 a = acc_o[mi][df];
          a[0] *= sc; a[1] *= sc; a[2] *= sc; a[3] *= sc;
          acc_o[mi][df] = a;
        }
      }
      float rs = 0.f;
#pragma unroll
      for (int jf = 0; jf < 4; ++jf)
#pragma unroll
        for (int r = 0; r < 4; ++r){
          float pe = fexp2(s[jf][r] - mn);
          s[jf][r] = pe;
          rs += pe;
        }
      rs += __shfl_xor(rs, 16);
      rs += __shfl_xor(rs, 32);
      lr[mi] += rs;
#pragma unroll
      for (int jf = 0; jf < 4; ++jf){
        w0[mi][jf] = pk_bf16(s[jf][0], s[jf][1]);
        w1[mi][jf] = pk_bf16(s[jf][2], s[jf][3]);
      }
    }

    // PV: ctx^T[d][q] += V^T[d][j] * P^T[j][q]; B-frag built in-register
#pragma unroll
    for (int kk = 0; kk < 2; ++kk){
#pragma unroll
      for (int mi = 0; mi < 2; ++mi){
        unsigned lo0 = (unsigned)__shfl((int)w0[mi][2*kk],   src0);
        unsigned hi0 = (unsigned)__shfl((int)w0[mi][2*kk+1], src0);
        unsigned lo1 = (unsigned)__shfl((int)w1[mi][2*kk],   src0);
        unsigned hi1 = (unsigned)__shfl((int)w1[mi][2*kk+1], src0);
        unsigned lo2 = (unsigned)__shfl((int)w0[mi][2*kk],   src1);
        unsigned hi2 = (unsigned)__shfl((int)w0[mi][2*kk+1], src1);
        unsigned lo3 = (unsigned)__shfl((int)w1[mi][2*kk],   src1);
        unsigned hi3 = (unsigned)__shfl((int)w1[mi][2*kk+1], src1);
        union { unsigned u[4]; short8 v; } pb;
        pb.u[0] = hiHalf ? hi0 : lo0;
        pb.u[1] = hiHalf ? hi1 : lo1;
        pb.u[2] = hiHalf ? hi2 : lo2;
        pb.u[3] = hiHalf ? hi3 : lo3;
#pragma unroll
        for (int df = 0; df < 4; ++df)
          acc_o[mi][df] = mfma16(vf[kk][df], pb.v, acc_o[mi][df]);
      }
    }
  }

  int bb = bh >> 4, h = bh & 15;
#pragma unroll
  for (int mi = 0; mi < 2; ++mi){
    float inv = 1.0f / lr[mi];
    int t = q0 + mi * 16 + (lane & 15);
#pragma unroll
    for (int df = 0; df < 4; ++df){
      int d0 = df * 16 + ((lane >> 4) << 2);
      f32x4 a = acc_o[mi][df];
      s16x4 o;
#pragma unroll
      for (int r = 0; r < 4; ++r) o[r] = (short)f2bf(a[r] * inv);
      *(s16x4*)(ctxb + ((size_t)(bb * T_ + t)) * 1024 + h * 64 + d0) = o;
    }
  }
}

// ---------------- output projection ----------------
__global__ __launch_bounds__(256) void k_oproj(const unsigned short* __restrict__ ctxb,
    const unsigned short* __restrict__ wob, const float* __restrict__ bo,
    float* __restrict__ out)
{
  __shared__ alignas(16) unsigned short lA[128 * 64];
  __shared__ alignas(16) unsigned short lB[128 * 64];
  int m0 = blockIdx.y * 128, n0 = blockIdx.x * 128;
  f32x4 acc[4][4];
  gemm_core(ctxb, wob, m0, n0, lA, lB, acc);
  int lane = threadIdx.x & 63, wave = threadIdx.x >> 6;
  int wr = wave >> 1, wc = wave & 1;
  for (int mi = 0; mi < 4; ++mi)
    for (int ni = 0; ni < 4; ++ni){
      int col = n0 + wc * 64 + ni * 16 + (lane & 15);
      float bsv = bo[col];
      f32x4 v4 = acc[mi][ni];
#pragma unroll
      for (int r = 0; r < 4; ++r){
        int m = m0 + wr * 64 + mi * 16 + ((lane >> 4) << 2) + r;
        out[(size_t)m * 1024 + col] = v4[r] + bsv;
      }
    }
}

extern "C" void kernel_launch(void* const* d_in, const int* in_sizes, int n_in,
                              void* d_out, int out_size, void* d_ws, size_t ws_size,
                              hipStream_t stream)
{
  const float* x  = (const float*)d_in[0];
  const float* wq = (const float*)d_in[1];
  const float* bq = (const float*)d_in[2];
  const float* wk = (const float*)d_in[3];
  const float* bk = (const float*)d_in[4];
  const float* wv = (const float*)d_in[5];
  const float* bv = (const float*)d_in[6];
  const float* wo = (const float*)d_in[7];
  const float* bo = (const float*)d_in[8];
  char* w = (char*)d_ws;
  unsigned short* xb   = (unsigned short*)(w);               // 8 MiB  [4096][1024]
  unsigned short* wqkv = (unsigned short*)(w + (8 << 20));   // 6 MiB  [3072][1024]
  unsigned short* wob  = (unsigned short*)(w + (14 << 20));  // 2 MiB
  unsigned short* Qw   = (unsigned short*)(w + (16 << 20));  // 8 MiB  [B,H,T,DK]
  unsigned short* Kw   = (unsigned short*)(w + (24 << 20));  // 8 MiB  [B,H,T,DK]
  unsigned short* Vw   = (unsigned short*)(w + (32 << 20));  // 8 MiB  [B,H,DK,T] (transposed!)
  unsigned short* ctxb = (unsigned short*)(w + (40 << 20));  // 8 MiB  [B,T,D]
  float* tab           = (float*)(w + (48 << 20));           // 512 KiB sin|cos

  k_prep<<<8192, 256, 0, stream>>>(x, wq, wk, wv, wo, xb, wqkv, wob, tab);
  k_qkv<<<dim3(24, 32), 256, 0, stream>>>(xb, wqkv, bq, bk, bv, tab, Qw, Kw, Vw);
  k_attn<<<2048, 64, 0, stream>>>(Qw, Kw, Vw, ctxb);
  k_oproj<<<dim3(8, 32), 256, 0, stream>>>(ctxb, wob, bo, (float*)d_out);
}

// Round 9
// 155.039 us; speedup vs baseline: 1.1023x; 1.1023x over previous
//
#include <hip/hip_runtime.h>
#include <stdint.h>
#include <stddef.h>

#define T_ 2048
#define D_ 1024
#define H_ 16

typedef __attribute__((ext_vector_type(8))) short short8;
typedef __attribute__((ext_vector_type(4))) float f32x4;
typedef __attribute__((ext_vector_type(4))) short s16x4;

__device__ __forceinline__ unsigned short f2bf(float f){
  union { float f; unsigned u; } c; c.f = f;
  unsigned u = c.u;
  return (unsigned short)((u + 0x7fffu + ((u >> 16) & 1u)) >> 16);
}

__device__ __forceinline__ unsigned pk_bf16(float lo, float hi){
  unsigned r;
  asm("v_cvt_pk_bf16_f32 %0, %1, %2" : "=v"(r) : "v"(lo), "v"(hi));
  return r;
}

__device__ __forceinline__ float fexp2(float x){
#if __has_builtin(__builtin_amdgcn_exp2f)
  return __builtin_amdgcn_exp2f(x);
#else
  return exp2f(x);
#endif
}

__device__ __forceinline__ f32x4 mfma16(short8 a, short8 b, f32x4 c){
  return __builtin_amdgcn_mfma_f32_16x16x32_bf16(a, b, c, 0, 0, 0);
}

// async global->LDS, 16B per lane; LDS dest must be uniform-base + lane*16
__device__ __forceinline__ void gload16(const void* g, void* l){
  __builtin_amdgcn_global_load_lds(
      (const __attribute__((address_space(1))) unsigned*)g,
      (__attribute__((address_space(3))) unsigned*)l, 16, 0, 0);
}

// ---------------- prep: f32 -> bf16 conversions + rope table ----------------
__global__ __launch_bounds__(256) void k_prep(const float* __restrict__ x,
    const float* __restrict__ wq, const float* __restrict__ wk,
    const float* __restrict__ wv, const float* __restrict__ wo,
    unsigned short* __restrict__ xb, unsigned short* __restrict__ wqkv,
    unsigned short* __restrict__ wob, float* __restrict__ tab)
{
  if (blockIdx.x < 256){                      // rope table [T][32] sin|cos
    int i = blockIdx.x * 256 + threadIdx.x;
    int t = i >> 5, p = i & 31;
    float ang = (float)t * powf(10000.0f, -(float)p * (1.0f / 32.0f));
    tab[i] = sinf(ang);
    tab[T_ * 32 + i] = cosf(ang);
  }
  const long long NX = 4194304LL, NW = 1048576LL;
  long long base = ((long long)blockIdx.x * 256 + threadIdx.x) * 4;
  const float* s; unsigned short* d;
  if (base < NX){ s = x + base; d = xb + base; }
  else if (base < NX + 3*NW){
    long long j = base - NX;
    if (j < NW) s = wq + j;
    else if (j < 2*NW) s = wk + (j - NW);
    else s = wv + (j - 2*NW);
    d = wqkv + j;
  } else if (base < NX + 4*NW){
    long long j = base - NX - 3*NW;
    s = wo + j; d = wob + j;
  } else return;
  float4 v = *(const float4*)s;
  d[0] = f2bf(v.x); d[1] = f2bf(v.y); d[2] = f2bf(v.z); d[3] = f2bf(v.w);
}

// ---------------- shared GEMM core: C[128x128] = A[128xK] * Bm[128xK]^T -------
__device__ __forceinline__ void gemm_core(const unsigned short* __restrict__ A,
    const unsigned short* __restrict__ Bm, int m0, int n0,
    unsigned short* lA, unsigned short* lB, f32x4 (&acc)[4][4])
{
  const int tid = threadIdx.x, lane = tid & 63, wave = tid >> 6;
  const int wr = wave >> 1, wc = wave & 1;
  for (int mi = 0; mi < 4; ++mi)
    for (int ni = 0; ni < 4; ++ni)
      acc[mi][ni] = (f32x4){0.f, 0.f, 0.f, 0.f};
  for (int k0 = 0; k0 < 1024; k0 += 64){
    __syncthreads();
#pragma unroll
    for (int p = 0; p < 4; ++p){
      int c = p * 256 + tid, r = c >> 3, s = c & 7;
      int gs = (s ^ (r & 7)) << 3;
      gload16(A + (size_t)(m0 + r) * 1024 + k0 + gs, lA + c * 8);
      gload16(Bm + (size_t)(n0 + r) * 1024 + k0 + gs, lB + c * 8);
    }
    __syncthreads();
#pragma unroll
    for (int kk = 0; kk < 2; ++kk){
      int kslot = kk * 4 + (lane >> 4);
      short8 af[4], bf[4];
#pragma unroll
      for (int mi = 0; mi < 4; ++mi){
        int row = wr * 64 + mi * 16 + (lane & 15);
        af[mi] = *(const short8*)(lA + row * 64 + ((kslot ^ (row & 7)) << 3));
      }
#pragma unroll
      for (int ni = 0; ni < 4; ++ni){
        int row = wc * 64 + ni * 16 + (lane & 15);
        bf[ni] = *(const short8*)(lB + row * 64 + ((kslot ^ (row & 7)) << 3));
      }
#pragma unroll
      for (int mi = 0; mi < 4; ++mi)
#pragma unroll
        for (int ni = 0; ni < 4; ++ni)
          acc[mi][ni] = mfma16(af[mi], bf[ni], acc[mi][ni]);
    }
  }
}

// ---------------- fused QKV projection + bias + RoPE ----------------
__global__ __launch_bounds__(256) void k_qkv(const unsigned short* __restrict__ xb,
    const unsigned short* __restrict__ wqkv,
    const float* __restrict__ bq, const float* __restrict__ bk, const float* __restrict__ bv,
    const float* __restrict__ tab,
    unsigned short* __restrict__ Qw, unsigned short* __restrict__ Kw,
    unsigned short* __restrict__ Vw)
{
  __shared__ alignas(16) unsigned short lA[128 * 64];
  __shared__ alignas(16) unsigned short lB[128 * 64];
  int m0 = blockIdx.y * 128, n0 = blockIdx.x * 128;
  f32x4 acc[4][4];
  gemm_core(xb, wqkv, m0, n0, lA, lB, acc);
  int lane = threadIdx.x & 63, wave = threadIdx.x >> 6;
  int wr = wave >> 1, wc = wave & 1;
  int mat = n0 >> 10;                       // 0=Q 1=K 2=V
  const float* bias = (mat == 0) ? bq : (mat == 1 ? bk : bv);
  const float* st = tab; const float* ct = tab + T_ * 32;
  if (mat < 2){
    unsigned short* Out = (mat == 0) ? Qw : Kw;
    float qs = (mat == 0) ? 0.18033688011116f : 1.0f;   // (1/8)*log2e
    for (int mi = 0; mi < 4; ++mi){
      for (int ni = 0; ni < 4; ++ni){
        int col = n0 + wc * 64 + ni * 16 + (lane & 15);
        int nn = col & 1023, h = nn >> 6, dd = nn & 63;
        float bsv = bias[nn];
        f32x4 v4 = acc[mi][ni];
#pragma unroll
        for (int r = 0; r < 4; ++r){
          int m = m0 + wr * 64 + mi * 16 + ((lane >> 4) << 2) + r;
          int bb = m >> 11, t = m & 2047;
          float v = v4[r] + bsv;
          float u = __shfl_xor(v, 1);       // rope partner col is lane^1
          int p = dd >> 1;
          float sv = st[t * 32 + p], cv = ct[t * 32 + p];
          float res = (dd & 1) ? (u * sv + v * cv) : (v * cv - u * sv);
          Out[((size_t)(bb * H_ + h) * T_ + t) * 64 + dd] = f2bf(res * qs);
        }
      }
    }
  } else {
    for (int mi = 0; mi < 4; ++mi){
      for (int ni = 0; ni < 4; ++ni){
        int col = n0 + wc * 64 + ni * 16 + (lane & 15);
        int nn = col & 1023, h = nn >> 6, dd = nn & 63;
        float bsv = bias[nn];
        int mb = m0 + wr * 64 + mi * 16 + ((lane >> 4) << 2);
        int bb = mb >> 11, t = mb & 2047;
        f32x4 v4 = acc[mi][ni];
        s16x4 o;
#pragma unroll
        for (int r = 0; r < 4; ++r) o[r] = (short)f2bf(v4[r] + bsv);
        *(s16x4*)(Vw + ((size_t)((bb * H_ + h) * 64 + dd)) * T_ + t) = o;
      }
    }
  }
}

// ---------------- flash attention (causal), split-KV within block -------------
// 8 waves: waves 0-3 process KV tiles [0, qt+1), waves 4-7 process
// [qt+1, 2qt+2), each half streaming its OWN K/V LDS buffer. Critical-path
// block drops from 32 to 16 barrier rendezvous; halves overlap each other's
// stage drains. Flash combine of (m,l,O) partials via LDS at the end.
__global__ __launch_bounds__(512) void k_attn(const unsigned short* __restrict__ Qw,
    const unsigned short* __restrict__ Kw, const unsigned short* __restrict__ Vt_g,
    unsigned short* __restrict__ ctxb)
{
  __shared__ alignas(16) unsigned short Kl[2][64 * 64];   // per-half [j][d] swizzled
  __shared__ alignas(16) unsigned short Vl[2][64 * 64];   // per-half [d][j] swizzled
  __shared__ float CB[4][64][36];                          // combine: [wv][lane][mi*18+{m,l,O16}]
  // XCD swizzle: 64 consecutive blocks per XCD = 4 bh x 16 qt; heavy qt first.
  int bid = blockIdx.x;
  int swz = (bid & 7) * 64 + (bid >> 3);
  int bh = swz >> 4;
  int qt = 15 - (swz & 15);
  int tid = threadIdx.x, lane = tid & 63, wave = tid >> 6;
  int hh = wave >> 2, wv = wave & 3;        // half, wave-within-half
  const unsigned short* Qb = Qw + (size_t)bh * T_ * 64;
  const unsigned short* Kb = Kw + (size_t)bh * T_ * 64;
  const unsigned short* Vb = Vt_g + (size_t)bh * 64 * T_;
  int q0 = qt * 128 + wv * 32;              // this wave's 32 q-rows

  short8 qf[2][2];
#pragma unroll
  for (int mi = 0; mi < 2; ++mi){
    const unsigned short* qp = Qb + (size_t)(q0 + mi * 16 + (lane & 15)) * 64 + ((lane >> 4) << 3);
    qf[mi][0] = *(const short8*)qp;
    qf[mi][1] = *(const short8*)(qp + 32);
  }
  float mr[2] = {-1e30f, -1e30f}, lr[2] = {0.f, 0.f};
  f32x4 acc_o[2][4];
#pragma unroll
  for (int mi = 0; mi < 2; ++mi)
#pragma unroll
    for (int df = 0; df < 4; ++df) acc_o[mi][df] = (f32x4){0.f, 0.f, 0.f, 0.f};

  const int src0 = ((lane >> 4) & 1) * 32 + (lane & 15);
  const int src1 = src0 + 16;
  const bool hiHalf = lane >= 32;
  const int tid_h = tid & 255;              // 256-thread cooperative id per half
  unsigned short* Kd = Kl[hh];
  unsigned short* Vd = Vl[hh];
  int niter = qt + 1;                       // per-half tile count (uniform)

  for (int i = 0; i < niter; ++i){
    int j0 = (hh ? (qt + 1 + i) : i) * 64;
    __syncthreads();                        // prev tile reads done (both halves)
#pragma unroll
    for (int p = 0; p < 2; ++p){
      int c = p * 256 + tid_h, r = c >> 3, s = c & 7;
      int gs = (s ^ (r & 7)) << 3;
      gload16(Kb + (size_t)(j0 + r) * 64 + gs, Kd + c * 8);
      gload16(Vb + (size_t)r * T_ + j0 + gs, Vd + c * 8);
    }
    __syncthreads();                        // tile resident
    if (j0 > q0 + 31) continue;             // causal skip (half1 wv<2 last tile)
    bool need_mask = (j0 + 63 > q0);

    // S^T = K @ Q^T : frag rows = j, cols = q (col = lane&15)
    f32x4 accs[2][4];
#pragma unroll
    for (int mi = 0; mi < 2; ++mi)
#pragma unroll
      for (int jf = 0; jf < 4; ++jf) accs[mi][jf] = (f32x4){0.f, 0.f, 0.f, 0.f};
#pragma unroll
    for (int kk = 0; kk < 2; ++kk){
      int kslot = kk * 4 + (lane >> 4);
      short8 kf[4];
#pragma unroll
      for (int jf = 0; jf < 4; ++jf){
        int row = jf * 16 + (lane & 15);
        kf[jf] = *(const short8*)(Kd + row * 64 + ((kslot ^ (row & 7)) << 3));
      }
#pragma unroll
      for (int mi = 0; mi < 2; ++mi)
#pragma unroll
        for (int jf = 0; jf < 4; ++jf)
          accs[mi][jf] = mfma16(kf[jf], qf[mi][kk], accs[mi][jf]);
    }

    // online softmax per q (lane-local for col q = lane&15), defer-max THR=8
    unsigned w0[2][4], w1[2][4];
#pragma unroll
    for (int mi = 0; mi < 2; ++mi){
      int qa = q0 + mi * 16 + (lane & 15);
      float s[4][4];
      float mx = -1e30f;
#pragma unroll
      for (int jf = 0; jf < 4; ++jf)
#pragma unroll
        for (int r = 0; r < 4; ++r){
          float sv = accs[mi][jf][r];
          if (need_mask){
            int ja = j0 + jf * 16 + ((lane >> 4) << 2) + r;
            if (ja > qa) sv = -1e30f;
          }
          s[jf][r] = sv;
          mx = fmaxf(mx, sv);
        }
      mx = fmaxf(mx, __shfl_xor(mx, 16));
      mx = fmaxf(mx, __shfl_xor(mx, 32));
      float mn = mr[mi];
      if (!__all(mx <= mn + 8.0f)){         // rescale only on real max growth
        mn = fmaxf(mn, mx);
        float sc = fexp2(mr[mi] - mn);
        mr[mi] = mn;
        lr[mi] *= sc;
#pragma unroll
        for (int df = 0; df < 4; ++df){
          f32x4 a = acc_o[mi][df];
          a[0] *= sc; a[1] *= sc; a[2] *= sc; a[3] *= sc;
          acc_o[mi][df] = a;
        }
      }
      float rs = 0.f;
#pragma unroll
      for (int jf = 0; jf < 4; ++jf)
#pragma unroll
        for (int r = 0; r < 4; ++r){
          float pe = fexp2(s[jf][r] - mn);
          s[jf][r] = pe;
          rs += pe;
        }
      rs += __shfl_xor(rs, 16);
      rs += __shfl_xor(rs, 32);
      lr[mi] += rs;
#pragma unroll
      for (int jf = 0; jf < 4; ++jf){
        w0[mi][jf] = pk_bf16(s[jf][0], s[jf][1]);
        w1[mi][jf] = pk_bf16(s[jf][2], s[jf][3]);
      }
    }

    // PV: ctx^T[d][q] += V^T[d][j] * P^T[j][q]; B-frag built in-register
#pragma unroll
    for (int kk = 0; kk < 2; ++kk){
      int jslot = kk * 4 + (lane >> 4);
      short8 vf[4];
#pragma unroll
      for (int df = 0; df < 4; ++df){
        int row = df * 16 + (lane & 15);
        vf[df] = *(const short8*)(Vd + row * 64 + ((jslot ^ (row & 7)) << 3));
      }
#pragma unroll
      for (int mi = 0; mi < 2; ++mi){
        unsigned lo0 = (unsigned)__shfl((int)w0[mi][2*kk],   src0);
        unsigned hi0 = (unsigned)__shfl((int)w0[mi][2*kk+1], src0);
        unsigned lo1 = (unsigned)__shfl((int)w1[mi][2*kk],   src0);
        unsigned hi1 = (unsigned)__shfl((int)w1[mi][2*kk+1], src0);
        unsigned lo2 = (unsigned)__shfl((int)w0[mi][2*kk],   src1);
        unsigned hi2 = (unsigned)__shfl((int)w0[mi][2*kk+1], src1);
        unsigned lo3 = (unsigned)__shfl((int)w1[mi][2*kk],   src1);
        unsigned hi3 = (unsigned)__shfl((int)w1[mi][2*kk+1], src1);
        union { unsigned u[4]; short8 v; } pb;
        pb.u[0] = hiHalf ? hi0 : lo0;
        pb.u[1] = hiHalf ? hi1 : lo1;
        pb.u[2] = hiHalf ? hi2 : lo2;
        pb.u[3] = hiHalf ? hi3 : lo3;
#pragma unroll
        for (int df = 0; df < 4; ++df)
          acc_o[mi][df] = mfma16(vf[df], pb.v, acc_o[mi][df]);
      }
    }
  }

  // ---- flash combine: half1 publishes (m,l,O), half0 merges and writes ----
  __syncthreads();
  if (hh == 1){
#pragma unroll
    for (int mi = 0; mi < 2; ++mi){
      CB[wv][lane][mi * 18 + 0] = mr[mi];
      CB[wv][lane][mi * 18 + 1] = lr[mi];
#pragma unroll
      for (int df = 0; df < 4; ++df)
#pragma unroll
        for (int r = 0; r < 4; ++r)
          CB[wv][lane][mi * 18 + 2 + df * 4 + r] = acc_o[mi][df][r];
    }
  }
  __syncthreads();
  if (hh == 0){
    int bb = bh >> 4, h = bh & 15;
#pragma unroll
    for (int mi = 0; mi < 2; ++mi){
      float m1 = CB[wv][lane][mi * 18 + 0];
      float l1 = CB[wv][lane][mi * 18 + 1];
      float m0 = mr[mi], l0 = lr[mi];
      float mfin = fmaxf(m0, m1);
      float a0 = fexp2(m0 - mfin), a1 = fexp2(m1 - mfin);
      float inv = 1.0f / (l0 * a0 + l1 * a1);
      int t = q0 + mi * 16 + (lane & 15);
#pragma unroll
      for (int df = 0; df < 4; ++df){
        int d0 = df * 16 + ((lane >> 4) << 2);
        s16x4 o;
#pragma unroll
        for (int r = 0; r < 4; ++r){
          float O = acc_o[mi][df][r] * a0 + CB[wv][lane][mi * 18 + 2 + df * 4 + r] * a1;
          o[r] = (short)f2bf(O * inv);
        }
        *(s16x4*)(ctxb + ((size_t)(bb * T_ + t)) * 1024 + h * 64 + d0) = o;
      }
    }
  }
}

// ---------------- output projection ----------------
__global__ __launch_bounds__(256) void k_oproj(const unsigned short* __restrict__ ctxb,
    const unsigned short* __restrict__ wob, const float* __restrict__ bo,
    float* __restrict__ out)
{
  __shared__ alignas(16) unsigned short lA[128 * 64];
  __shared__ alignas(16) unsigned short lB[128 * 64];
  int m0 = blockIdx.y * 128, n0 = blockIdx.x * 128;
  f32x4 acc[4][4];
  gemm_core(ctxb, wob, m0, n0, lA, lB, acc);
  int lane = threadIdx.x & 63, wave = threadIdx.x >> 6;
  int wr = wave >> 1, wc = wave & 1;
  for (int mi = 0; mi < 4; ++mi)
    for (int ni = 0; ni < 4; ++ni){
      int col = n0 + wc * 64 + ni * 16 + (lane & 15);
      float bsv = bo[col];
      f32x4 v4 = acc[mi][ni];
#pragma unroll
      for (int r = 0; r < 4; ++r){
        int m = m0 + wr * 64 + mi * 16 + ((lane >> 4) << 2) + r;
        out[(size_t)m * 1024 + col] = v4[r] + bsv;
      }
    }
}

extern "C" void kernel_launch(void* const* d_in, const int* in_sizes, int n_in,
                              void* d_out, int out_size, void* d_ws, size_t ws_size,
                              hipStream_t stream)
{
  const float* x  = (const float*)d_in[0];
  const float* wq = (const float*)d_in[1];
  const float* bq = (const float*)d_in[2];
  const float* wk = (const float*)d_in[3];
  const float* bk = (const float*)d_in[4];
  const float* wv = (const float*)d_in[5];
  const float* bv = (const float*)d_in[6];
  const float* wo = (const float*)d_in[7];
  const float* bo = (const float*)d_in[8];
  char* w = (char*)d_ws;
  unsigned short* xb   = (unsigned short*)(w);               // 8 MiB  [4096][1024]
  unsigned short* wqkv = (unsigned short*)(w + (8 << 20));   // 6 MiB  [3072][1024]
  unsigned short* wob  = (unsigned short*)(w + (14 << 20));  // 2 MiB
  unsigned short* Qw   = (unsigned short*)(w + (16 << 20));  // 8 MiB  [B,H,T,DK]
  unsigned short* Kw   = (unsigned short*)(w + (24 << 20));  // 8 MiB  [B,H,T,DK]
  unsigned short* Vw   = (unsigned short*)(w + (32 << 20));  // 8 MiB  [B,H,DK,T] (transposed!)
  unsigned short* ctxb = (unsigned short*)(w + (40 << 20));  // 8 MiB  [B,T,D]
  float* tab           = (float*)(w + (48 << 20));           // 512 KiB sin|cos

  k_prep<<<8192, 256, 0, stream>>>(x, wq, wk, wv, wo, xb, wqkv, wob, tab);
  k_qkv<<<dim3(24, 32), 256, 0, stream>>>(xb, wqkv, bq, bk, bv, tab, Qw, Kw, Vw);
  k_attn<<<512, 512, 0, stream>>>(Qw, Kw, Vw, ctxb);
  k_oproj<<<dim3(8, 32), 256, 0, stream>>>(ctxb, wob, bo, (float*)d_out);
}